// Round 9
// baseline (120.179 us; speedup 1.0000x reference)
//
#include <hip/hip_runtime.h>

// ---- problem constants ----
constexpr int  Bn    = 512;
constexpr int  Dd    = 128;
constexpr int  QUEUE = 65536;
constexpr int  NEGR  = 8192;              // B*N in-batch negatives
constexpr int  NJ    = NEGR + QUEUE;      // 73728 negative columns
constexpr long long OUTC    = 1 + NJ;     // 73729 out row stride
constexpr long long MEM_OFF = 2LL * Bn * OUTC;  // new_memory offset in d_out

// single fused kernel; block ranges ordered so streaming copy starts FIRST
// (interleaves with gemm ramp) and gemm blocks (high wave-parallelism) finish.
constexpr int MEM_BLK  = 256;             // [0,256)    memory-queue copy
constexpr int POS_BLK  = Bn / 4;          // [256,384)  positive logits
constexpr int GEMM_BLK = NJ / 256;        // [384,672)  288 gemm blocks, 256 cols
constexpr int TOT_BLK  = MEM_BLK + POS_BLK + GEMM_BLK;

constexpr int LDS_STRIDE = 260;           // 16x256 f32 tile; 1040B row pitch
                                          // (16B-aligned rows for ds_read_b128)

typedef __attribute__((ext_vector_type(8))) short  short8;
typedef __attribute__((ext_vector_type(4))) float  floatx4;

__device__ __forceinline__ unsigned short f2bf(float f) {
    union { float f; unsigned u; } x; x.f = f;
    unsigned u = x.u;
    u += 0x7fffu + ((u >> 16) & 1u);   // round-to-nearest-even
    return (unsigned short)(u >> 16);
}

__device__ __forceinline__ short8 pack8(float4 a, float4 b) {
    short8 r;
    r[0] = (short)f2bf(a.x); r[1] = (short)f2bf(a.y);
    r[2] = (short)f2bf(a.z); r[3] = (short)f2bf(a.w);
    r[4] = (short)f2bf(b.x); r[5] = (short)f2bf(b.y);
    r[6] = (short)f2bf(b.z); r[7] = (short)f2bf(b.w);
    return r;
}

// ---- fused kernel: [0,256) mem copy | [256,384) pos col | [384,672) gemm ----
__global__ __launch_bounds__(256) void fused(const float* __restrict__ q,
                                             const float* __restrict__ negs,
                                             const float* __restrict__ mem,
                                             const float* __restrict__ k,
                                             const float* __restrict__ ps,
                                             const float* __restrict__ k_all,
                                             const int* __restrict__ indexp,
                                             float* __restrict__ out) {
    __shared__ float tile[16 * LDS_STRIDE];   // 16.6 KB, only used by gemm blocks

    const int blk  = blockIdx.x;
    const int lane = threadIdx.x & 63;
    const int wave = threadIdx.x >> 6;

    if (blk >= MEM_BLK + POS_BLK) {
        // ---- GEMM: 256 cols/block, 64 cols/wave (4 j-groups of 16) ----
        // A is converted f32->bf16 in-register per m-tile (q is L1/L2-resident;
        // replaces the separate qconv dispatch).
        const int g    = blk - (MEM_BLK + POS_BLK);   // 0..287
        const int l16  = lane & 15;
        const int kg   = lane >> 4;        // 0..3
        const int klo  = kg * 8;
        // XCD swizzle: 288 = 8 * 36 -> adjacent stripes on same XCD's L2
        const int stripe = (g & 7) * 36 + (g >> 3);
        const long long jbase0 = (long long)stripe * 256;          // block col base
        const long long jbase  = jbase0 + wave * 64;               // wave col base

        // B fragments: 4 j-groups x 4 k-slices; converted f32->bf16 in regs
        short8 bfrag[4][4];
        #pragma unroll
        for (int gg = 0; gg < 4; ++gg) {
            const long long jrow = jbase + gg * 16 + l16;
            const float* src = (jrow < NEGR) ? (negs + jrow * Dd)
                                             : (mem + (jrow - NEGR) * Dd);
            #pragma unroll
            for (int s = 0; s < 4; ++s) {
                float4 x = *(const float4*)(src + s * 32 + klo);
                float4 y = *(const float4*)(src + s * 32 + klo + 4);
                bfrag[gg][s] = pack8(x, y);
            }
        }

        #pragma unroll 1
        for (int m = 0; m < 32; ++m) {
            // A fragments from f32 q, converted in-register (RNE, bit-identical
            // to the old qconv output)
            const float* arow = q + (long long)(m * 16 + l16) * Dd + klo;
            short8 af[4];
            #pragma unroll
            for (int s = 0; s < 4; ++s) {
                float4 x = *(const float4*)(arow + s * 32);
                float4 y = *(const float4*)(arow + s * 32 + 4);
                af[s] = pack8(x, y);
            }
            // compute 16 values/thread, scale, stage into LDS (transpose via LDS:
            // MFMA layout scatters a wave over 4 rows -> misaligned 64B segments)
            #pragma unroll
            for (int gg = 0; gg < 4; ++gg) {
                floatx4 acc = {0.f, 0.f, 0.f, 0.f};
                #pragma unroll
                for (int s = 0; s < 4; ++s)
                    acc = __builtin_amdgcn_mfma_f32_16x16x32_bf16(af[s], bfrag[gg][s], acc, 0, 0, 0);
                const int tcol = wave * 64 + gg * 16 + l16;
                #pragma unroll
                for (int r = 0; r < 4; ++r)
                    tile[(kg * 4 + r) * LDS_STRIDE + tcol] = acc[r] * 10.0f;
            }
            __syncthreads();
            // cooperative write-out, dwordx4: wave w -> tile rows {w, w+4, w+8, w+12};
            // ds_read_b128 then one global_store_dwordx4 per lane covers the whole
            // 1KB row run.
            #pragma unroll
            for (int i = 0; i < 4; ++i) {
                const int trow = i * 4 + wave;
                const float4 v = *(const float4*)&tile[trow * LDS_STRIDE + lane * 4];
                const long long grow = (long long)(m * 16 + trow);
                float* dst = out + grow * OUTC + 1 + jbase0 + lane * 4;
                *(float4*)dst                 = v;   // dword-aligned dwordx4: OK on gfx950
                *(float4*)(dst + Bn * OUTC)   = v;
            }
            __syncthreads();
        }
    } else if (blk >= MEM_BLK) {
        // ---- positive logits -> out column 0 (one wave per batch row) ----
        const int b = (blk - MEM_BLK) * 4 + wave;
        float2 qv = *(const float2*)(q + (long long)b * Dd + lane * 2);
        float2 kv = *(const float2*)(k + (long long)b * Dd + lane * 2);
        float pk = qv.x * kv.x + qv.y * kv.y;
        float pp = 0.f;
        #pragma unroll
        for (int p = 0; p < 4; ++p) {
            float2 pv = *(const float2*)(ps + ((long long)b * 4 + p) * Dd + lane * 2);
            pp += qv.x * pv.x + qv.y * pv.y;
        }
        #pragma unroll
        for (int off = 32; off; off >>= 1) {
            pk += __shfl_xor(pk, off);
            pp += __shfl_xor(pp, off);
        }
        if (lane == 0) {
            out[(long long)b * OUTC]        = pk * 10.0f;
            out[((long long)b + Bn) * OUTC] = (pp * 0.25f) * 10.0f;
        }
    } else {
        // ---- new_memory = memory with rows (i+index)%Q <- k_all[i] ----
        // dispatched FIRST so the 67MB copy stream interleaves with gemm ramp-up
        float* outmem = out + MEM_OFF;
        const int index = *indexp;
        const long long total = (long long)QUEUE * (Dd / 4);   // float4 chunks
        const long long stride = (long long)MEM_BLK * 256;
        for (long long i = (long long)blk * 256 + threadIdx.x; i < total; i += stride) {
            int row = (int)(i >> 5);          // D/4 = 32 chunks per row
            int c4  = (int)(i & 31);
            int src = (row - index) & (QUEUE - 1);
            float4 v;
            if (src < Bn) v = *(const float4*)(k_all + (long long)src * Dd + c4 * 4);
            else          v = *(const float4*)(mem   + (long long)row * Dd + c4 * 4);
            *(float4*)(outmem + (long long)row * Dd + c4 * 4) = v;
        }
    }
}

extern "C" void kernel_launch(void* const* d_in, const int* in_sizes, int n_in,
                              void* d_out, int out_size, void* d_ws, size_t ws_size,
                              hipStream_t stream) {
    const float* q      = (const float*)d_in[0];
    const float* k      = (const float*)d_in[1];
    const float* pos    = (const float*)d_in[2];
    const float* negs   = (const float*)d_in[3];
    const float* k_all  = (const float*)d_in[4];
    const float* memory = (const float*)d_in[5];
    const int*   indexp = (const int*)d_in[6];
    float* out = (float*)d_out;

    fused<<<TOT_BLK, 256, 0, stream>>>(q, negs, memory, k, pos, k_all, indexp, out);
}

// Round 11
// 93.970 us; speedup vs baseline: 1.2789x; 1.2789x over previous
//
#include <hip/hip_runtime.h>

// ---- problem constants ----
constexpr int  Bn    = 512;
constexpr int  Dd    = 128;
constexpr int  QUEUE = 65536;
constexpr int  NEGR  = 8192;              // B*N in-batch negatives
constexpr int  NJ    = NEGR + QUEUE;      // 73728 negative columns
constexpr long long OUTC    = 1 + NJ;     // 73729 out row stride
constexpr long long MEM_OFF = 2LL * Bn * OUTC;  // new_memory offset in d_out

// EXACT R7 structure (proven 83.9us): qconv separate; gemm blocks first.
// Single change vs R7: non-temporal (evict-first) hints on the write-once
// out/new_memory stores to stop the 302MB write stream thrashing L2.
constexpr int GEMM_BLK = NJ / 256;        // 288 blocks, 256 cols each
constexpr int POS_BLK  = Bn / 4;          // 128 blocks, 4 rows each (4 waves)
constexpr int MEM_BLK  = 256;             // grid-stride memory-copy blocks
constexpr int TOT_BLK  = GEMM_BLK + POS_BLK + MEM_BLK;

constexpr int LDS_STRIDE = 260;           // 16x256 f32 tile; 1040B row pitch

typedef __attribute__((ext_vector_type(8))) short  short8;
typedef __attribute__((ext_vector_type(4))) float  floatx4;

__device__ __forceinline__ unsigned short f2bf(float f) {
    union { float f; unsigned u; } x; x.f = f;
    unsigned u = x.u;
    u += 0x7fffu + ((u >> 16) & 1u);   // round-to-nearest-even
    return (unsigned short)(u >> 16);
}

__device__ __forceinline__ short8 pack8(float4 a, float4 b) {
    short8 r;
    r[0] = (short)f2bf(a.x); r[1] = (short)f2bf(a.y);
    r[2] = (short)f2bf(a.z); r[3] = (short)f2bf(a.w);
    r[4] = (short)f2bf(b.x); r[5] = (short)f2bf(b.y);
    r[6] = (short)f2bf(b.z); r[7] = (short)f2bf(b.w);
    return r;
}

// nt store via ext_vector_type pointer (clang builtin rejects HIP_vector_type*)
__device__ __forceinline__ void st_nt(float* p, floatx4 v) {
    __builtin_nontemporal_store(v, (floatx4*)p);
}

// ---- kernel 0: q (512x128 f32) -> bf16 in workspace ----
__global__ void qconv(const float* __restrict__ q, unsigned short* __restrict__ qb) {
    int t = blockIdx.x * blockDim.x + threadIdx.x;      // 16384 threads, 4 elems each
    float4 v = *(const float4*)(q + (long long)t * 4);
    ushort4 r;
    r.x = f2bf(v.x); r.y = f2bf(v.y); r.z = f2bf(v.z); r.w = f2bf(v.w);
    *(ushort4*)(qb + (long long)t * 4) = r;
}

// ---- fused kernel: [0,288) gemm | [288,416) positive col | [416,672) memory copy ----
__global__ __launch_bounds__(256) void fused(const unsigned short* __restrict__ qb,
                                             const float* __restrict__ negs,
                                             const float* __restrict__ mem,
                                             const float* __restrict__ q,
                                             const float* __restrict__ k,
                                             const float* __restrict__ ps,
                                             const float* __restrict__ k_all,
                                             const int* __restrict__ indexp,
                                             float* __restrict__ out) {
    __shared__ float tile[16 * LDS_STRIDE];   // 16.6 KB, only used by gemm blocks

    const int blk  = blockIdx.x;
    const int lane = threadIdx.x & 63;
    const int wave = threadIdx.x >> 6;

    if (blk < GEMM_BLK) {
        // ---- GEMM: 256 cols/block, 64 cols/wave (4 j-groups of 16) ----
        const int l16 = lane & 15;
        const int kg  = lane >> 4;        // 0..3
        const int klo = kg * 8;
        // XCD swizzle: 288 = 8 * 36 -> adjacent stripes on same XCD's L2
        const int stripe = (blk & 7) * 36 + (blk >> 3);
        const long long jbase0 = (long long)stripe * 256;          // block col base
        const long long jbase  = jbase0 + wave * 64;               // wave col base

        // B fragments: 4 j-groups x 4 k-slices; converted f32->bf16 in regs
        short8 bfrag[4][4];
        #pragma unroll
        for (int g = 0; g < 4; ++g) {
            const long long jrow = jbase + g * 16 + l16;
            const float* src = (jrow < NEGR) ? (negs + jrow * Dd)
                                             : (mem + (jrow - NEGR) * Dd);
            #pragma unroll
            for (int s = 0; s < 4; ++s) {
                float4 x = *(const float4*)(src + s * 32 + klo);
                float4 y = *(const float4*)(src + s * 32 + klo + 4);
                bfrag[g][s] = pack8(x, y);
            }
        }

        #pragma unroll 1
        for (int m = 0; m < 32; ++m) {
            const unsigned short* arow = qb + (long long)(m * 16 + l16) * Dd + klo;
            short8 af[4];
            #pragma unroll
            for (int s = 0; s < 4; ++s) af[s] = *(const short8*)(arow + s * 32);
            // compute 16 values/thread, scale, stage into LDS (transpose via LDS:
            // MFMA layout scatters a wave over 4 rows -> misaligned 64B segments)
            #pragma unroll
            for (int g = 0; g < 4; ++g) {
                floatx4 acc = {0.f, 0.f, 0.f, 0.f};
                #pragma unroll
                for (int s = 0; s < 4; ++s)
                    acc = __builtin_amdgcn_mfma_f32_16x16x32_bf16(af[s], bfrag[g][s], acc, 0, 0, 0);
                const int tcol = wave * 64 + g * 16 + l16;
                #pragma unroll
                for (int r = 0; r < 4; ++r)
                    tile[(kg * 4 + r) * LDS_STRIDE + tcol] = acc[r] * 10.0f;
            }
            __syncthreads();
            // cooperative write-out, dwordx4 + nt (write-once stream, evict-first):
            // wave w -> tile rows {w, w+4, w+8, w+12}; one 1KB run per row
            #pragma unroll
            for (int i = 0; i < 4; ++i) {
                const int trow = i * 4 + wave;
                const floatx4 v = *(const floatx4*)&tile[trow * LDS_STRIDE + lane * 4];
                const long long grow = (long long)(m * 16 + trow);
                float* dst = out + grow * OUTC + 1 + jbase0 + lane * 4;
                st_nt(dst, v);
                st_nt(dst + Bn * OUTC, v);
            }
            __syncthreads();
        }
    } else if (blk < GEMM_BLK + POS_BLK) {
        // ---- positive logits -> out column 0 (one wave per batch row) ----
        const int b = (blk - GEMM_BLK) * 4 + wave;
        float2 qv = *(const float2*)(q + (long long)b * Dd + lane * 2);
        float2 kv = *(const float2*)(k + (long long)b * Dd + lane * 2);
        float pk = qv.x * kv.x + qv.y * kv.y;
        float pp = 0.f;
        #pragma unroll
        for (int p = 0; p < 4; ++p) {
            float2 pv = *(const float2*)(ps + ((long long)b * 4 + p) * Dd + lane * 2);
            pp += qv.x * pv.x + qv.y * pv.y;
        }
        #pragma unroll
        for (int off = 32; off; off >>= 1) {
            pk += __shfl_xor(pk, off);
            pp += __shfl_xor(pp, off);
        }
        if (lane == 0) {
            out[(long long)b * OUTC]        = pk * 10.0f;
            out[((long long)b + Bn) * OUTC] = (pp * 0.25f) * 10.0f;
        }
    } else {
        // ---- new_memory = memory with rows (i+index)%Q <- k_all[i] ----
        float* outmem = out + MEM_OFF;
        const int index = *indexp;
        const long long total = (long long)QUEUE * (Dd / 4);   // float4 chunks
        const long long stride = (long long)MEM_BLK * 256;
        for (long long i = (long long)(blk - GEMM_BLK - POS_BLK) * 256 + threadIdx.x;
             i < total; i += stride) {
            int row = (int)(i >> 5);          // D/4 = 32 chunks per row
            int c4  = (int)(i & 31);
            int src = (row - index) & (QUEUE - 1);
            floatx4 v;
            if (src < Bn) v = *(const floatx4*)(k_all + (long long)src * Dd + c4 * 4);
            else          v = *(const floatx4*)(mem   + (long long)row * Dd + c4 * 4);
            st_nt(outmem + (long long)row * Dd + c4 * 4, v);
        }
    }
}

extern "C" void kernel_launch(void* const* d_in, const int* in_sizes, int n_in,
                              void* d_out, int out_size, void* d_ws, size_t ws_size,
                              hipStream_t stream) {
    const float* q      = (const float*)d_in[0];
    const float* k      = (const float*)d_in[1];
    const float* pos    = (const float*)d_in[2];
    const float* negs   = (const float*)d_in[3];
    const float* k_all  = (const float*)d_in[4];
    const float* memory = (const float*)d_in[5];
    const int*   indexp = (const int*)d_in[6];
    float* out = (float*)d_out;
    unsigned short* qb = (unsigned short*)d_ws;   // 512*128*2 = 128 KB

    qconv<<<64, 256, 0, stream>>>(q, qb);
    fused<<<TOT_BLK, 256, 0, stream>>>(qb, negs, memory, q, k, pos, k_all, indexp, out);
}

// Round 12
// 82.895 us; speedup vs baseline: 1.4498x; 1.1336x over previous
//
#include <hip/hip_runtime.h>

// ---- problem constants ----
constexpr int  Bn    = 512;
constexpr int  Dd    = 128;
constexpr int  QUEUE = 65536;
constexpr int  NEGR  = 8192;              // B*N in-batch negatives
constexpr int  NJ    = NEGR + QUEUE;      // 73728 negative columns
constexpr long long OUTC    = 1 + NJ;     // 73729 out row stride
constexpr long long MEM_OFF = 2LL * Bn * OUTC;  // new_memory offset in d_out

// R7 structure (proven 83.9us; nt-stores REVERTED — R11 showed evict-first
// breaks L2 write-merging, +10us). Single change vs R7: double-buffered LDS
// tile -> ONE barrier per m-tile; the vmcnt(0) drain before each barrier now
// lands one full m-tile after the stores were issued (store latency hidden).
constexpr int GEMM_BLK = NJ / 256;        // 288 blocks, 256 cols each
constexpr int POS_BLK  = Bn / 4;          // 128 blocks, 4 rows each (4 waves)
constexpr int MEM_BLK  = 256;             // grid-stride memory-copy blocks
constexpr int TOT_BLK  = GEMM_BLK + POS_BLK + MEM_BLK;

constexpr int LDS_STRIDE = 260;           // 16x256 f32 tile; 1040B row pitch

typedef __attribute__((ext_vector_type(8))) short  short8;
typedef __attribute__((ext_vector_type(4))) float  floatx4;

__device__ __forceinline__ unsigned short f2bf(float f) {
    union { float f; unsigned u; } x; x.f = f;
    unsigned u = x.u;
    u += 0x7fffu + ((u >> 16) & 1u);   // round-to-nearest-even
    return (unsigned short)(u >> 16);
}

__device__ __forceinline__ short8 pack8(float4 a, float4 b) {
    short8 r;
    r[0] = (short)f2bf(a.x); r[1] = (short)f2bf(a.y);
    r[2] = (short)f2bf(a.z); r[3] = (short)f2bf(a.w);
    r[4] = (short)f2bf(b.x); r[5] = (short)f2bf(b.y);
    r[6] = (short)f2bf(b.z); r[7] = (short)f2bf(b.w);
    return r;
}

// ---- kernel 0: q (512x128 f32) -> bf16 in workspace ----
__global__ void qconv(const float* __restrict__ q, unsigned short* __restrict__ qb) {
    int t = blockIdx.x * blockDim.x + threadIdx.x;      // 16384 threads, 4 elems each
    float4 v = *(const float4*)(q + (long long)t * 4);
    ushort4 r;
    r.x = f2bf(v.x); r.y = f2bf(v.y); r.z = f2bf(v.z); r.w = f2bf(v.w);
    *(ushort4*)(qb + (long long)t * 4) = r;
}

// ---- fused kernel: [0,288) gemm | [288,416) positive col | [416,672) memory copy ----
__global__ __launch_bounds__(256) void fused(const unsigned short* __restrict__ qb,
                                             const float* __restrict__ negs,
                                             const float* __restrict__ mem,
                                             const float* __restrict__ q,
                                             const float* __restrict__ k,
                                             const float* __restrict__ ps,
                                             const float* __restrict__ k_all,
                                             const int* __restrict__ indexp,
                                             float* __restrict__ out) {
    __shared__ float tile[2][16 * LDS_STRIDE];   // 33.3 KB double buffer (gemm only)

    const int blk  = blockIdx.x;
    const int lane = threadIdx.x & 63;
    const int wave = threadIdx.x >> 6;

    if (blk < GEMM_BLK) {
        // ---- GEMM: 256 cols/block, 64 cols/wave (4 j-groups of 16) ----
        const int l16 = lane & 15;
        const int kg  = lane >> 4;        // 0..3
        const int klo = kg * 8;
        // XCD swizzle: 288 = 8 * 36 -> adjacent stripes on same XCD's L2
        const int stripe = (blk & 7) * 36 + (blk >> 3);
        const long long jbase0 = (long long)stripe * 256;          // block col base
        const long long jbase  = jbase0 + wave * 64;               // wave col base

        // B fragments: 4 j-groups x 4 k-slices; converted f32->bf16 in regs
        short8 bfrag[4][4];
        #pragma unroll
        for (int g = 0; g < 4; ++g) {
            const long long jrow = jbase + g * 16 + l16;
            const float* src = (jrow < NEGR) ? (negs + jrow * Dd)
                                             : (mem + (jrow - NEGR) * Dd);
            #pragma unroll
            for (int s = 0; s < 4; ++s) {
                float4 x = *(const float4*)(src + s * 32 + klo);
                float4 y = *(const float4*)(src + s * 32 + klo + 4);
                bfrag[g][s] = pack8(x, y);
            }
        }

        #pragma unroll 1
        for (int m = 0; m < 32; ++m) {
            float* tb = tile[m & 1];      // current staging buffer
            const unsigned short* arow = qb + (long long)(m * 16 + l16) * Dd + klo;
            short8 af[4];
            #pragma unroll
            for (int s = 0; s < 4; ++s) af[s] = *(const short8*)(arow + s * 32);
            // compute 16 values/thread, scale, stage into LDS (transpose via LDS:
            // MFMA layout scatters a wave over 4 rows -> misaligned 64B segments)
            #pragma unroll
            for (int g = 0; g < 4; ++g) {
                floatx4 acc = {0.f, 0.f, 0.f, 0.f};
                #pragma unroll
                for (int s = 0; s < 4; ++s)
                    acc = __builtin_amdgcn_mfma_f32_16x16x32_bf16(af[s], bfrag[g][s], acc, 0, 0, 0);
                const int tcol = wave * 64 + g * 16 + l16;
                #pragma unroll
                for (int r = 0; r < 4; ++r)
                    tb[(kg * 4 + r) * LDS_STRIDE + tcol] = acc[r] * 10.0f;
            }
            // ONE barrier per m-tile: staging of tile[m&1] complete. The implicit
            // vmcnt(0) here drains the stores issued at iter m-1 — a full m-tile
            // of compute covered their latency. Buffer re-stage at m+2 is safe:
            // each wave's own ds_reads drained by this barrier's lgkmcnt(0).
            __syncthreads();
            // cooperative write-out, dwordx4: wave w -> tile rows {w,w+4,w+8,w+12};
            // one 1KB-contiguous run per row
            #pragma unroll
            for (int i = 0; i < 4; ++i) {
                const int trow = i * 4 + wave;
                const float4 v = *(const float4*)&tb[trow * LDS_STRIDE + lane * 4];
                const long long grow = (long long)(m * 16 + trow);
                float* dst = out + grow * OUTC + 1 + jbase0 + lane * 4;
                *(float4*)dst               = v;
                *(float4*)(dst + Bn * OUTC) = v;
            }
        }
    } else if (blk < GEMM_BLK + POS_BLK) {
        // ---- positive logits -> out column 0 (one wave per batch row) ----
        const int b = (blk - GEMM_BLK) * 4 + wave;
        float2 qv = *(const float2*)(q + (long long)b * Dd + lane * 2);
        float2 kv = *(const float2*)(k + (long long)b * Dd + lane * 2);
        float pk = qv.x * kv.x + qv.y * kv.y;
        float pp = 0.f;
        #pragma unroll
        for (int p = 0; p < 4; ++p) {
            float2 pv = *(const float2*)(ps + ((long long)b * 4 + p) * Dd + lane * 2);
            pp += qv.x * pv.x + qv.y * pv.y;
        }
        #pragma unroll
        for (int off = 32; off; off >>= 1) {
            pk += __shfl_xor(pk, off);
            pp += __shfl_xor(pp, off);
        }
        if (lane == 0) {
            out[(long long)b * OUTC]        = pk * 10.0f;
            out[((long long)b + Bn) * OUTC] = (pp * 0.25f) * 10.0f;
        }
    } else {
        // ---- new_memory = memory with rows (i+index)%Q <- k_all[i] ----
        float* outmem = out + MEM_OFF;
        const int index = *indexp;
        const long long total = (long long)QUEUE * (Dd / 4);   // float4 chunks
        const long long stride = (long long)MEM_BLK * 256;
        for (long long i = (long long)(blk - GEMM_BLK - POS_BLK) * 256 + threadIdx.x;
             i < total; i += stride) {
            int row = (int)(i >> 5);          // D/4 = 32 chunks per row
            int c4  = (int)(i & 31);
            int src = (row - index) & (QUEUE - 1);
            float4 v;
            if (src < Bn) v = *(const float4*)(k_all + (long long)src * Dd + c4 * 4);
            else          v = *(const float4*)(mem   + (long long)row * Dd + c4 * 4);
            *(float4*)(outmem + (long long)row * Dd + c4 * 4) = v;
        }
    }
}

extern "C" void kernel_launch(void* const* d_in, const int* in_sizes, int n_in,
                              void* d_out, int out_size, void* d_ws, size_t ws_size,
                              hipStream_t stream) {
    const float* q      = (const float*)d_in[0];
    const float* k      = (const float*)d_in[1];
    const float* pos    = (const float*)d_in[2];
    const float* negs   = (const float*)d_in[3];
    const float* k_all  = (const float*)d_in[4];
    const float* memory = (const float*)d_in[5];
    const int*   indexp = (const int*)d_in[6];
    float* out = (float*)d_out;
    unsigned short* qb = (unsigned short*)d_ws;   // 512*128*2 = 128 KB

    qconv<<<64, 256, 0, stream>>>(q, qb);
    fused<<<TOT_BLK, 256, 0, stream>>>(qb, negs, memory, q, k, pos, k_all, indexp, out);
}